// Round 12
// baseline (562.118 us; speedup 1.0000x reference)
//
#include <hip/hip_runtime.h>

// LightGCN forward, D=64, N=150k, NNZ=6M, 3 layers.
// Pipeline: fused count+reserve+scatter into fixed-capacity buckets ->
// per-bucket counting sort (self-computed prefix, pair loads) -> gather
// SpMM v5: wave processes TWO rows concurrently (16 accumulators) so the
// per-row serial latency (off load -> metadata -> gather chain) of one row
// hides under the other's independent loads. Octet-split gathers (lane =
// (o,t), uint4 = 8 bf16 dims), main/tail split per row.
// bf16 propagated embeddings. acc pre-scaled by 0.25 at init. etmp (54.5MB,
// padded) aliases bufA/bufB; consumed by csr_sort before init writes them.

#define U_CNT 100000
#define I_CNT 50000
#define N_CNT 150000
#define DIM 64
#define NNZ_CNT 6000000
#define NSEL 4096

#define NBKT 512
#define BROWS 293                 // 512*293 = 150016 >= 150000
// exact: bkt = (row * 114521) >> 25 for row < 151830
#define BKT_OF(r) ((int)(((unsigned long long)(unsigned)(r) * 114521ull) >> 25))
#define BCAP 13312                // bucket capacity: mean 11719, sigma 108

#define BIN_BLK 512
#define BIN_THR 256

__device__ __forceinline__ unsigned short f32_to_bf16_rne(float f) {
    unsigned u = __float_as_uint(f);
    u += 0x7FFFu + ((u >> 16) & 1u);      // round-to-nearest-even
    return (unsigned short)(u >> 16);
}
__device__ __forceinline__ float bf16_lo(unsigned u) {
    return __uint_as_float(u << 16);
}
__device__ __forceinline__ float bf16_hi(unsigned u) {
    return __uint_as_float(u & 0xFFFF0000u);
}

// ---------------- small kernels ----------------

// init: cur = bf16(ego) ; acc = 0.25 * ego (f32, pre-scaled)
__global__ void init_kernel(const float* __restrict__ user_emb,
                            const float* __restrict__ item_emb,
                            unsigned short* __restrict__ cur,
                            float* __restrict__ acc) {
    const int total = N_CNT * DIM / 4;
    const int ubound = U_CNT * DIM / 4;
    const float4* ue = (const float4*)user_emb;
    const float4* ie = (const float4*)item_emb;
    float4* a4 = (float4*)acc;
    ushort4* c4 = (ushort4*)cur;
    for (int i = blockIdx.x * blockDim.x + threadIdx.x; i < total;
         i += gridDim.x * blockDim.x) {
        float4 v = (i < ubound) ? ue[i] : ie[i - ubound];
        ushort4 cv;
        cv.x = f32_to_bf16_rne(v.x);
        cv.y = f32_to_bf16_rne(v.y);
        cv.z = f32_to_bf16_rne(v.z);
        cv.w = f32_to_bf16_rne(v.w);
        c4[i] = cv;
        float4 a = v;
        a.x *= 0.25f; a.y *= 0.25f; a.z *= 0.25f; a.w *= 0.25f;
        a4[i] = a;
    }
}

__global__ void gather_kernel(const float* __restrict__ final_emb,
                              const int* __restrict__ users,
                              const int* __restrict__ pos,
                              const int* __restrict__ neg,
                              float* __restrict__ out) {
    const int total = 3 * NSEL * (DIM / 4);
    const float4* f4 = (const float4*)final_emb;
    float4* o4 = (float4*)out;
    for (int i = blockIdx.x * blockDim.x + threadIdx.x; i < total;
         i += gridDim.x * blockDim.x) {
        const int rowi = i / (DIM / 4);
        const int d4 = i % (DIM / 4);
        int src;
        if (rowi < NSEL) {
            src = users[rowi];
        } else if (rowi < 2 * NSEL) {
            src = U_CNT + pos[rowi - NSEL];
        } else {
            src = U_CNT + neg[rowi - 2 * NSEL];
        }
        o4[i] = f4[src * (DIM / 4) + d4];
    }
}

// ---------------- phase 1: fused count + reserve + scatter ----------------

__global__ void bin_scatter_kernel(const float* __restrict__ val,
                                   const int* __restrict__ row,
                                   const int* __restrict__ col,
                                   int* __restrict__ gcnt,
                                   int2* __restrict__ etmp) {
    __shared__ int h[NBKT];
    __shared__ int curs[NBKT];
    for (int i = threadIdx.x; i < NBKT; i += BIN_THR) h[i] = 0;
    __syncthreads();
    const int tid = blockIdx.x * BIN_THR + threadIdx.x;
    const int4* r4 = (const int4*)row;
    const int4* c4 = (const int4*)col;
    const float4* v4 = (const float4*)val;
    // count pass
    for (int g = tid; g < NNZ_CNT / 4; g += BIN_BLK * BIN_THR) {
        const int4 r = r4[g];
        atomicAdd(&h[BKT_OF(r.x)], 1);
        atomicAdd(&h[BKT_OF(r.y)], 1);
        atomicAdd(&h[BKT_OF(r.z)], 1);
        atomicAdd(&h[BKT_OF(r.w)], 1);
    }
    __syncthreads();
    // reserve runs
    for (int i = threadIdx.x; i < NBKT; i += BIN_THR) {
        const int c = h[i];
        int base = 0;
        if (c > 0) base = atomicAdd(&gcnt[i], c);
        curs[i] = i * BCAP + base;
    }
    __syncthreads();
    // write pass
    for (int g = tid; g < NNZ_CNT / 4; g += BIN_BLK * BIN_THR) {
        const int4 r = r4[g];
        const int4 c = c4[g];
        const float4 v = v4[g];
        {
            const int bk = BKT_OF(r.x);
            const int p = atomicAdd(&curs[bk], 1);
            etmp[p] = make_int2(c.x | ((r.x - bk * BROWS) << 18),
                                __float_as_int(v.x));
        }
        {
            const int bk = BKT_OF(r.y);
            const int p = atomicAdd(&curs[bk], 1);
            etmp[p] = make_int2(c.y | ((r.y - bk * BROWS) << 18),
                                __float_as_int(v.y));
        }
        {
            const int bk = BKT_OF(r.z);
            const int p = atomicAdd(&curs[bk], 1);
            etmp[p] = make_int2(c.z | ((r.z - bk * BROWS) << 18),
                                __float_as_int(v.z));
        }
        {
            const int bk = BKT_OF(r.w);
            const int p = atomicAdd(&curs[bk], 1);
            etmp[p] = make_int2(c.w | ((r.w - bk * BROWS) << 18),
                                __float_as_int(v.w));
        }
    }
}

// ---------------- phase 2: per-bucket counting sort -> compact CSR -------
// Self-computed prefix (sums gcnt[0..bkt) in-block; deletes scan_tot kernel).
// Pair (int4) loads in count and scatter passes.
__global__ __launch_bounds__(1024) void csr_sort_kernel(
        const int2* __restrict__ etmp,
        const int* __restrict__ gcnt,
        int2* __restrict__ edges,
        int* __restrict__ off) {
    __shared__ int cnt[BROWS];
    __shared__ int start[BROWS];
    __shared__ int sc[1024];
    const int bkt = blockIdx.x;
    const int tid = threadIdx.x;
    const int n = gcnt[bkt];
    const int sbeg = bkt * BCAP;

    // dbeg = exclusive prefix of gcnt over buckets [0, bkt)
    sc[tid] = (tid < bkt) ? gcnt[tid] : 0;
    __syncthreads();
    for (int d = 512; d >= 1; d >>= 1) {
        if (tid < d) sc[tid] += sc[tid + d];
        __syncthreads();
    }
    const int dbeg = sc[0];
    __syncthreads();

    for (int i = tid; i < BROWS; i += 1024) cnt[i] = 0;
    __syncthreads();
    const int npair = n >> 1;
    const int4* et4 = (const int4*)(etmp + sbeg);
    for (int p = tid; p < npair; p += 1024) {
        const int4 ed = et4[p];
        atomicAdd(&cnt[((unsigned)ed.x) >> 18], 1);
        atomicAdd(&cnt[((unsigned)ed.z) >> 18], 1);
    }
    if (tid == 0 && (n & 1))
        atomicAdd(&cnt[((unsigned)etmp[sbeg + n - 1].x) >> 18], 1);
    __syncthreads();
    {   // parallel exclusive scan of cnt[0..BROWS) padded to 1024
        const int v = (tid < BROWS) ? cnt[tid] : 0;
        sc[tid] = v;
        __syncthreads();
        for (int d = 1; d < 1024; d <<= 1) {
            int t = (tid >= d) ? sc[tid - d] : 0;
            __syncthreads();
            sc[tid] += t;
            __syncthreads();
        }
        if (tid < BROWS) start[tid] = sc[tid] - v;
    }
    __syncthreads();
    const int base_row = bkt * BROWS;
    for (int i = tid; i < BROWS; i += 1024) {
        if (base_row + i < N_CNT) off[base_row + i] = dbeg + start[i];
        cnt[i] = start[i];                   // cnt becomes cursor
    }
    if (bkt == 0 && tid == 0) off[N_CNT] = NNZ_CNT;
    __syncthreads();
    for (int p = tid; p < npair; p += 1024) {
        const int4 ed = et4[p];
        int rl = ((unsigned)ed.x) >> 18;
        int q = atomicAdd(&cnt[rl], 1);
        edges[dbeg + q] = make_int2(ed.x & 0x3FFFF, ed.y);
        rl = ((unsigned)ed.z) >> 18;
        q = atomicAdd(&cnt[rl], 1);
        edges[dbeg + q] = make_int2(ed.z & 0x3FFFF, ed.w);
    }
    if (tid == 0 && (n & 1)) {
        const int2 ed = etmp[sbeg + n - 1];
        const int rl = ((unsigned)ed.x) >> 18;
        const int q = atomicAdd(&cnt[rl], 1);
        edges[dbeg + q] = make_int2(ed.x & 0x3FFFF, ed.y);
    }
}

// ---------------- gather SpMM v5 (2 rows/wave interleaved) ----------------

__device__ __forceinline__ void block16(const int2* __restrict__ edges,
                                        int e0, int o,
                                        const unsigned short* __restrict__ xt,
                                        float (&s)[8]) {
    const int2 eva = edges[e0 + o];              // 8B bcast per octet
    const int2 evb = edges[e0 + o + 8];
    const float va = __int_as_float(eva.y);
    const float vb = __int_as_float(evb.y);
    const uint4 xa = *(const uint4*)(xt + ((size_t)(unsigned)eva.x << 6));
    const uint4 xb = *(const uint4*)(xt + ((size_t)(unsigned)evb.x << 6));
    s[0] += va * bf16_lo(xa.x); s[1] += va * bf16_hi(xa.x);
    s[2] += va * bf16_lo(xa.y); s[3] += va * bf16_hi(xa.y);
    s[4] += va * bf16_lo(xa.z); s[5] += va * bf16_hi(xa.z);
    s[6] += va * bf16_lo(xa.w); s[7] += va * bf16_hi(xa.w);
    s[0] += vb * bf16_lo(xb.x); s[1] += vb * bf16_hi(xb.x);
    s[2] += vb * bf16_lo(xb.y); s[3] += vb * bf16_hi(xb.y);
    s[4] += vb * bf16_lo(xb.z); s[5] += vb * bf16_hi(xb.z);
    s[6] += vb * bf16_lo(xb.w); s[7] += vb * bf16_hi(xb.w);
}

__device__ __forceinline__ void tail16(const int2* __restrict__ edges,
                                       int mend, int end, int o,
                                       const unsigned short* __restrict__ xt,
                                       float (&s)[8]) {
    const int ea = mend + o;
    const int eb = ea + 8;
    int2 eva = make_int2(0, 0), evb = make_int2(0, 0);
    if (ea < end) eva = edges[ea];
    if (eb < end) evb = edges[eb];
    const float va = __int_as_float(eva.y);
    const float vb = __int_as_float(evb.y);
    const uint4 xa = *(const uint4*)(xt + ((size_t)(unsigned)eva.x << 6));
    const uint4 xb = *(const uint4*)(xt + ((size_t)(unsigned)evb.x << 6));
    s[0] += va * bf16_lo(xa.x); s[1] += va * bf16_hi(xa.x);
    s[2] += va * bf16_lo(xa.y); s[3] += va * bf16_hi(xa.y);
    s[4] += va * bf16_lo(xa.z); s[5] += va * bf16_hi(xa.z);
    s[6] += va * bf16_lo(xa.w); s[7] += va * bf16_hi(xa.w);
    s[0] += vb * bf16_lo(xb.x); s[1] += vb * bf16_hi(xb.x);
    s[2] += vb * bf16_lo(xb.y); s[3] += vb * bf16_hi(xb.y);
    s[4] += vb * bf16_lo(xb.z); s[5] += vb * bf16_hi(xb.z);
    s[6] += vb * bf16_lo(xb.w); s[7] += vb * bf16_hi(xb.w);
}

__device__ __forceinline__ void reduce_write(float (&s)[8], int r, int lane,
                                             int t,
                                             unsigned short* __restrict__ y,
                                             float* __restrict__ acc,
                                             int write_y) {
    #pragma unroll
    for (int i = 0; i < 8; ++i) {
        s[i] += __shfl_xor(s[i], 8);
        s[i] += __shfl_xor(s[i], 16);
        s[i] += __shfl_xor(s[i], 32);
    }
    if (lane < 8) {                              // o == 0, t == lane
        if (write_y) {
            uint4 cv;
            cv.x = (unsigned)f32_to_bf16_rne(s[0]) |
                   ((unsigned)f32_to_bf16_rne(s[1]) << 16);
            cv.y = (unsigned)f32_to_bf16_rne(s[2]) |
                   ((unsigned)f32_to_bf16_rne(s[3]) << 16);
            cv.z = (unsigned)f32_to_bf16_rne(s[4]) |
                   ((unsigned)f32_to_bf16_rne(s[5]) << 16);
            cv.w = (unsigned)f32_to_bf16_rne(s[6]) |
                   ((unsigned)f32_to_bf16_rne(s[7]) << 16);
            ((uint4*)(y + ((size_t)r << 6)))[t] = cv;
        }
        float4* a4 = (float4*)(acc + ((size_t)r << 6) + (t << 3));
        float4 a0 = a4[0];
        float4 a1 = a4[1];
        a0.x += 0.25f * s[0]; a0.y += 0.25f * s[1];
        a0.z += 0.25f * s[2]; a0.w += 0.25f * s[3];
        a1.x += 0.25f * s[4]; a1.y += 0.25f * s[5];
        a1.z += 0.25f * s[6]; a1.w += 0.25f * s[7];
        a4[0] = a0;
        a4[1] = a1;
    }
}

// Wave processes rows r0 and r0+totalWaves concurrently: the interleaved
// main loop keeps both rows' gathers in flight, hiding each row's serial
// off->metadata->gather dependency chain under the other's work.
__global__ void spmm_csr_kernel(const int2* __restrict__ edges,
                                const int* __restrict__ off,
                                const unsigned short* __restrict__ x,
                                unsigned short* __restrict__ y,
                                float* __restrict__ acc,
                                int write_y) {
    const int lane = threadIdx.x & 63;
    const int o = lane >> 3;
    const int t = lane & 7;
    const int gw = (blockIdx.x * blockDim.x + threadIdx.x) >> 6;
    const int totalWaves = (gridDim.x * blockDim.x) >> 6;
    const unsigned short* xt = x + (t << 3);
    for (int r0 = gw; r0 < N_CNT; r0 += 2 * totalWaves) {
        const int r1 = r0 + totalWaves;
        const int begA = off[r0];
        const int endA = off[r0 + 1];
        int begB = 0, endB = 0;
        if (r1 < N_CNT) { begB = off[r1]; endB = off[r1 + 1]; }
        const int mendA = begA + ((endA - begA) & ~15);
        const int mendB = begB + ((endB - begB) & ~15);
        float sA[8] = {0.f, 0.f, 0.f, 0.f, 0.f, 0.f, 0.f, 0.f};
        float sB[8] = {0.f, 0.f, 0.f, 0.f, 0.f, 0.f, 0.f, 0.f};
        int eA = begA, eB = begB;
        while (eA < mendA && eB < mendB) {       // interleaved: 4 gathers live
            block16(edges, eA, o, xt, sA);
            block16(edges, eB, o, xt, sB);
            eA += 16; eB += 16;
        }
        #pragma unroll 2
        for (; eA < mendA; eA += 16) block16(edges, eA, o, xt, sA);
        #pragma unroll 2
        for (; eB < mendB; eB += 16) block16(edges, eB, o, xt, sB);
        if (eA < endA) tail16(edges, eA, endA, o, xt, sA);
        if (eB < endB) tail16(edges, eB, endB, o, xt, sB);
        reduce_write(sA, r0, lane, t, y, acc, write_y);
        if (r1 < N_CNT) reduce_write(sB, r1, lane, t, y, acc, write_y);
    }
}

// ---------------- fallback (scatter-atomic, f32 path) ----------------

__global__ void init_f32_kernel(const float* __restrict__ user_emb,
                                const float* __restrict__ item_emb,
                                float* __restrict__ cur,
                                float* __restrict__ acc) {
    const int total = N_CNT * DIM / 4;
    const int ubound = U_CNT * DIM / 4;
    const float4* ue = (const float4*)user_emb;
    const float4* ie = (const float4*)item_emb;
    float4* c4 = (float4*)cur;
    float4* a4 = (float4*)acc;
    for (int i = blockIdx.x * blockDim.x + threadIdx.x; i < total;
         i += gridDim.x * blockDim.x) {
        float4 v = (i < ubound) ? ue[i] : ie[i - ubound];
        c4[i] = v;
        float4 a = v;
        a.x *= 0.25f; a.y *= 0.25f; a.z *= 0.25f; a.w *= 0.25f;
        a4[i] = a;
    }
}

__global__ void spmm_atomic_kernel(const float* __restrict__ val,
                                   const int* __restrict__ row,
                                   const int* __restrict__ col,
                                   const float* __restrict__ x,
                                   float* __restrict__ y) {
    const int lane = threadIdx.x & 63;
    const int gw = (blockIdx.x * blockDim.x + threadIdx.x) >> 6;
    const int totalWaves = (gridDim.x * blockDim.x) >> 6;
    for (int base = gw * 64; base < NNZ_CNT; base += totalWaves * 64) {
        const int e = base + lane;
        const float v = val[e];
        const int r = row[e];
        const int c = col[e];
        #pragma unroll 8
        for (int k = 0; k < 64; ++k) {
            const float vk = __shfl(v, k);
            const int rk = __shfl(r, k);
            const int ck = __shfl(c, k);
            atomicAdd(&y[rk * DIM + lane], vk * x[ck * DIM + lane]);
        }
    }
}

__global__ void accum_scale_kernel(float* __restrict__ acc,
                                   const float* __restrict__ nxt,
                                   float wacc) {
    const int total = N_CNT * DIM / 4;
    float4* a4 = (float4*)acc;
    const float4* n4 = (const float4*)nxt;
    for (int i = blockIdx.x * blockDim.x + threadIdx.x; i < total;
         i += gridDim.x * blockDim.x) {
        float4 a = a4[i];
        const float4 n = n4[i];
        a.x += wacc * n.x; a.y += wacc * n.y; a.z += wacc * n.z; a.w += wacc * n.w;
        a4[i] = a;
    }
}

// ---------------- launch ----------------

extern "C" void kernel_launch(void* const* d_in, const int* in_sizes, int n_in,
                              void* d_out, int out_size, void* d_ws, size_t ws_size,
                              hipStream_t stream) {
    const float* user_emb  = (const float*)d_in[0];
    const float* item_emb  = (const float*)d_in[1];
    const float* adj_val   = (const float*)d_in[2];
    const int*   adj_row   = (const int*)d_in[3];
    const int*   adj_col   = (const int*)d_in[4];
    const int*   users     = (const int*)d_in[5];
    const int*   pos_items = (const int*)d_in[6];
    const int*   neg_items = (const int*)d_in[7];
    // d_in[8] = num_layers, fixed at 3 (device scalar; host read would break
    // graph capture).

    float* out       = (float*)d_out;
    float* out_sel   = out;
    float* final_emb = out + (size_t)3 * NSEL * DIM;   // u_g then i_g
    float* acc       = final_emb;

    const size_t NBH = (size_t)N_CNT * DIM * 2;        // bf16 buf: 19,200,000
    char* ws = (char*)d_ws;
    // etmp (padded, 54.5MB) occupies ws[0:offE]; bufA/bufB (bf16, 38.4MB)
    // alias its front and are only written after csr_sort consumed etmp.
    int2* etmp = (int2*)(ws + 0);
    unsigned short* bufA = (unsigned short*)(ws + 0);
    unsigned short* bufB = (unsigned short*)(ws + NBH);

    const size_t offE    = (size_t)NBKT * BCAP * 8;          // 54,525,952
    const size_t offG    = offE + (size_t)NNZ_CNT * 8;       // gcnt 2KB
    const size_t offOff  = offG + 4096;                      // off[N+1]
    const size_t needed  = offOff + (size_t)(N_CNT + 1) * 4 + 64;

    if (ws_size >= needed) {
        int2* edges = (int2*)(ws + offE);
        int*  gcnt  = (int*)(ws + offG);
        int*  offp  = (int*)(ws + offOff);

        (void)hipMemsetAsync(gcnt, 0, NBKT * sizeof(int), stream);
        bin_scatter_kernel<<<BIN_BLK, BIN_THR, 0, stream>>>(adj_val, adj_row,
                                                            adj_col, gcnt,
                                                            etmp);
        csr_sort_kernel<<<NBKT, 1024, 0, stream>>>(etmp, gcnt, edges, offp);

        init_kernel<<<2048, 256, 0, stream>>>(user_emb, item_emb, bufA, acc);

        unsigned short* cur = bufA;
        unsigned short* nxt = bufB;
        for (int l = 0; l < 3; ++l) {
            spmm_csr_kernel<<<2048, 256, 0, stream>>>(edges, offp, cur, nxt, acc,
                                                      (l < 2) ? 1 : 0);
            unsigned short* t = cur; cur = nxt; nxt = t;
        }
    } else {
        // f32 scatter-atomic fallback (needs 2*38.4MB of ws)
        float* fA = (float*)(ws + 0);
        float* fB = (float*)(ws + (size_t)N_CNT * DIM * sizeof(float));
        init_f32_kernel<<<2048, 256, 0, stream>>>(user_emb, item_emb, fA, acc);
        float* cur = fA;
        float* nxt = fB;
        for (int l = 0; l < 3; ++l) {
            (void)hipMemsetAsync(nxt, 0, (size_t)N_CNT * DIM * sizeof(float),
                                 stream);
            spmm_atomic_kernel<<<2048, 256, 0, stream>>>(adj_val, adj_row,
                                                         adj_col, cur, nxt);
            accum_scale_kernel<<<2048, 256, 0, stream>>>(acc, nxt, 0.25f);
            float* t = cur; cur = nxt; nxt = t;
        }
    }

    gather_kernel<<<768, 256, 0, stream>>>(final_emb, users, pos_items,
                                           neg_items, out_sel);
}

// Round 13
// 468.075 us; speedup vs baseline: 1.2009x; 1.2009x over previous
//
#include <hip/hip_runtime.h>

// LightGCN forward, D=64, N=150k, NNZ=6M, 3 layers.
// ROUND-11 CONFIGURATION (best measured: 464.9us) — reverted after the v5
// 2-row-interleave experiment dropped occupancy 80->47% and regressed spmm
// 112->139us (TLP > ILP in this latency-bound regime), and the csr_sort
// self-prefix cost ~17us.
// Pipeline: fused count+reserve+scatter into fixed-capacity buckets (512
// buckets x BCAP slots) -> 512-scan of bucket counts -> per-bucket counting
// sort to row-ordered compact CSR -> gather SpMM v4 (wave per row,
// octet-split, 16 edges/iter, main/tail split, 32 gathers in flight).
// bf16 propagated embeddings. acc pre-scaled by 0.25 at init. etmp (54.5MB,
// padded) aliases bufA/bufB; consumed by csr_sort before init writes them.

#define U_CNT 100000
#define I_CNT 50000
#define N_CNT 150000
#define DIM 64
#define NNZ_CNT 6000000
#define NSEL 4096

#define NBKT 512
#define BROWS 293                 // 512*293 = 150016 >= 150000
// exact: bkt = (row * 114521) >> 25 for row < 151830
#define BKT_OF(r) ((int)(((unsigned long long)(unsigned)(r) * 114521ull) >> 25))
#define BCAP 13312                // bucket capacity: mean 11719, sigma 108

#define BIN_BLK 512
#define BIN_THR 256

__device__ __forceinline__ unsigned short f32_to_bf16_rne(float f) {
    unsigned u = __float_as_uint(f);
    u += 0x7FFFu + ((u >> 16) & 1u);      // round-to-nearest-even
    return (unsigned short)(u >> 16);
}
__device__ __forceinline__ float bf16_lo(unsigned u) {
    return __uint_as_float(u << 16);
}
__device__ __forceinline__ float bf16_hi(unsigned u) {
    return __uint_as_float(u & 0xFFFF0000u);
}

// ---------------- small kernels ----------------

// init: cur = bf16(ego) ; acc = 0.25 * ego (f32, pre-scaled)
__global__ void init_kernel(const float* __restrict__ user_emb,
                            const float* __restrict__ item_emb,
                            unsigned short* __restrict__ cur,
                            float* __restrict__ acc) {
    const int total = N_CNT * DIM / 4;
    const int ubound = U_CNT * DIM / 4;
    const float4* ue = (const float4*)user_emb;
    const float4* ie = (const float4*)item_emb;
    float4* a4 = (float4*)acc;
    ushort4* c4 = (ushort4*)cur;
    for (int i = blockIdx.x * blockDim.x + threadIdx.x; i < total;
         i += gridDim.x * blockDim.x) {
        float4 v = (i < ubound) ? ue[i] : ie[i - ubound];
        ushort4 cv;
        cv.x = f32_to_bf16_rne(v.x);
        cv.y = f32_to_bf16_rne(v.y);
        cv.z = f32_to_bf16_rne(v.z);
        cv.w = f32_to_bf16_rne(v.w);
        c4[i] = cv;
        float4 a = v;
        a.x *= 0.25f; a.y *= 0.25f; a.z *= 0.25f; a.w *= 0.25f;
        a4[i] = a;
    }
}

__global__ void gather_kernel(const float* __restrict__ final_emb,
                              const int* __restrict__ users,
                              const int* __restrict__ pos,
                              const int* __restrict__ neg,
                              float* __restrict__ out) {
    const int total = 3 * NSEL * (DIM / 4);
    const float4* f4 = (const float4*)final_emb;
    float4* o4 = (float4*)out;
    for (int i = blockIdx.x * blockDim.x + threadIdx.x; i < total;
         i += gridDim.x * blockDim.x) {
        const int rowi = i / (DIM / 4);
        const int d4 = i % (DIM / 4);
        int src;
        if (rowi < NSEL) {
            src = users[rowi];
        } else if (rowi < 2 * NSEL) {
            src = U_CNT + pos[rowi - NSEL];
        } else {
            src = U_CNT + neg[rowi - 2 * NSEL];
        }
        o4[i] = f4[src * (DIM / 4) + d4];
    }
}

// ---------------- phase 1: fused count + reserve + scatter ----------------
// Per block: LDS histogram of its edge chunk -> one global atomicAdd per
// touched bucket reserves a contiguous run in that bucket's fixed-capacity
// region -> write pass via LDS cursors. Contiguous ~23-edge runs per
// (block,bucket) keep the write frontier L2-resident (no partial-line HBM
// amplification).
__global__ void bin_scatter_kernel(const float* __restrict__ val,
                                   const int* __restrict__ row,
                                   const int* __restrict__ col,
                                   int* __restrict__ gcnt,
                                   int2* __restrict__ etmp) {
    __shared__ int h[NBKT];
    __shared__ int curs[NBKT];
    for (int i = threadIdx.x; i < NBKT; i += BIN_THR) h[i] = 0;
    __syncthreads();
    const int tid = blockIdx.x * BIN_THR + threadIdx.x;
    const int4* r4 = (const int4*)row;
    const int4* c4 = (const int4*)col;
    const float4* v4 = (const float4*)val;
    // count pass
    for (int g = tid; g < NNZ_CNT / 4; g += BIN_BLK * BIN_THR) {
        const int4 r = r4[g];
        atomicAdd(&h[BKT_OF(r.x)], 1);
        atomicAdd(&h[BKT_OF(r.y)], 1);
        atomicAdd(&h[BKT_OF(r.z)], 1);
        atomicAdd(&h[BKT_OF(r.w)], 1);
    }
    __syncthreads();
    // reserve runs
    for (int i = threadIdx.x; i < NBKT; i += BIN_THR) {
        const int c = h[i];
        int base = 0;
        if (c > 0) base = atomicAdd(&gcnt[i], c);
        curs[i] = i * BCAP + base;
    }
    __syncthreads();
    // write pass
    for (int g = tid; g < NNZ_CNT / 4; g += BIN_BLK * BIN_THR) {
        const int4 r = r4[g];
        const int4 c = c4[g];
        const float4 v = v4[g];
        {
            const int bk = BKT_OF(r.x);
            const int p = atomicAdd(&curs[bk], 1);
            etmp[p] = make_int2(c.x | ((r.x - bk * BROWS) << 18),
                                __float_as_int(v.x));
        }
        {
            const int bk = BKT_OF(r.y);
            const int p = atomicAdd(&curs[bk], 1);
            etmp[p] = make_int2(c.y | ((r.y - bk * BROWS) << 18),
                                __float_as_int(v.y));
        }
        {
            const int bk = BKT_OF(r.z);
            const int p = atomicAdd(&curs[bk], 1);
            etmp[p] = make_int2(c.z | ((r.z - bk * BROWS) << 18),
                                __float_as_int(v.z));
        }
        {
            const int bk = BKT_OF(r.w);
            const int p = atomicAdd(&curs[bk], 1);
            etmp[p] = make_int2(c.w | ((r.w - bk * BROWS) << 18),
                                __float_as_int(v.w));
        }
    }
}

// One block: exclusive scan of the 512 bucket counts -> boff[0..512]
// (compact CSR bucket bases).
__global__ void scan_tot_kernel(const int* __restrict__ gcnt,
                                int* __restrict__ boff) {
    __shared__ int s[NBKT];
    const int k = threadIdx.x;
    const int v = gcnt[k];
    s[k] = v;
    __syncthreads();
    for (int d = 1; d < NBKT; d <<= 1) {
        int t = (k >= d) ? s[k - d] : 0;
        __syncthreads();
        s[k] += t;
        __syncthreads();
    }
    boff[k] = s[k] - v;
    if (k == NBKT - 1) boff[NBKT] = s[k];
}

// ---------------- phase 2: per-bucket counting sort -> compact CSR -------
// Reads padded etmp region [bkt*BCAP, bkt*BCAP + gcnt[bkt]); writes compact
// edges at boff[bkt].
__global__ __launch_bounds__(1024) void csr_sort_kernel(
        const int2* __restrict__ etmp,
        const int* __restrict__ gcnt,
        const int* __restrict__ boff,
        int2* __restrict__ edges,
        int* __restrict__ off) {
    __shared__ int cnt[BROWS];
    __shared__ int start[BROWS];
    __shared__ int sc[1024];
    const int bkt = blockIdx.x;
    const int n = gcnt[bkt];
    const int sbeg = bkt * BCAP;
    const int dbeg = boff[bkt];
    const int tid = threadIdx.x;

    for (int i = tid; i < BROWS; i += 1024) cnt[i] = 0;
    __syncthreads();
    for (int e = tid; e < n; e += 1024)
        atomicAdd(&cnt[((unsigned)etmp[sbeg + e].x) >> 18], 1);
    __syncthreads();
    {   // parallel exclusive scan of cnt[0..BROWS) padded to 1024
        const int v = (tid < BROWS) ? cnt[tid] : 0;
        sc[tid] = v;
        __syncthreads();
        for (int d = 1; d < 1024; d <<= 1) {
            int t = (tid >= d) ? sc[tid - d] : 0;
            __syncthreads();
            sc[tid] += t;
            __syncthreads();
        }
        if (tid < BROWS) start[tid] = sc[tid] - v;
    }
    __syncthreads();
    const int base_row = bkt * BROWS;
    for (int i = tid; i < BROWS; i += 1024) {
        if (base_row + i < N_CNT) off[base_row + i] = dbeg + start[i];
        cnt[i] = start[i];                   // cnt becomes cursor
    }
    if (bkt == 0 && tid == 0) off[N_CNT] = NNZ_CNT;
    __syncthreads();
    for (int e = tid; e < n; e += 1024) {
        const int2 ed = etmp[sbeg + e];
        const int rl = ((unsigned)ed.x) >> 18;
        const int p = atomicAdd(&cnt[rl], 1);
        edges[dbeg + p] = make_int2(ed.x & 0x3FFFF, ed.y);
    }
}

// ---------------- gather SpMM v4 (16 edges/iter, main/tail split) --------
// Wave per row. lane = (o = lane>>3, t = lane&7). Octet o processes edges
// e0+o and e0+8+o; lane gathers uint4 = 8 bf16 (dims 8t..8t+7). Main loop
// over full 16-blocks has NO bounds checks (unroll 2 -> 32 gathers in
// flight); one masked tail block. Octet partials via shfl_xor 8/16/32.
__global__ void spmm_csr_kernel(const int2* __restrict__ edges,
                                const int* __restrict__ off,
                                const unsigned short* __restrict__ x,
                                unsigned short* __restrict__ y,
                                float* __restrict__ acc,
                                int write_y) {
    const int lane = threadIdx.x & 63;
    const int o = lane >> 3;
    const int t = lane & 7;
    const int gw = (blockIdx.x * blockDim.x + threadIdx.x) >> 6;
    const int totalWaves = (gridDim.x * blockDim.x) >> 6;
    const unsigned short* xt = x + (t << 3);
    for (int r = gw; r < N_CNT; r += totalWaves) {
        const int beg = off[r];
        const int end = off[r + 1];
        const int nfull = (end - beg) & ~15;
        const int mend = beg + nfull;
        float s0 = 0.f, s1 = 0.f, s2 = 0.f, s3 = 0.f;
        float s4 = 0.f, s5 = 0.f, s6 = 0.f, s7 = 0.f;
        #pragma unroll 2
        for (int e0 = beg; e0 < mend; e0 += 16) {
            const int2 eva = edges[e0 + o];          // 8B bcast per octet
            const int2 evb = edges[e0 + o + 8];
            const float va = __int_as_float(eva.y);
            const float vb = __int_as_float(evb.y);
            const uint4 xa = *(const uint4*)(xt + ((size_t)(unsigned)eva.x << 6));
            const uint4 xb = *(const uint4*)(xt + ((size_t)(unsigned)evb.x << 6));
            s0 += va * bf16_lo(xa.x); s1 += va * bf16_hi(xa.x);
            s2 += va * bf16_lo(xa.y); s3 += va * bf16_hi(xa.y);
            s4 += va * bf16_lo(xa.z); s5 += va * bf16_hi(xa.z);
            s6 += va * bf16_lo(xa.w); s7 += va * bf16_hi(xa.w);
            s0 += vb * bf16_lo(xb.x); s1 += vb * bf16_hi(xb.x);
            s2 += vb * bf16_lo(xb.y); s3 += vb * bf16_hi(xb.y);
            s4 += vb * bf16_lo(xb.z); s5 += vb * bf16_hi(xb.z);
            s6 += vb * bf16_lo(xb.w); s7 += vb * bf16_hi(xb.w);
        }
        if (mend < end) {                            // masked tail block
            const int ea = mend + o;
            const int eb = ea + 8;
            int2 eva = make_int2(0, 0), evb = make_int2(0, 0);
            if (ea < end) eva = edges[ea];
            if (eb < end) evb = edges[eb];
            const float va = __int_as_float(eva.y);
            const float vb = __int_as_float(evb.y);
            const uint4 xa = *(const uint4*)(xt + ((size_t)(unsigned)eva.x << 6));
            const uint4 xb = *(const uint4*)(xt + ((size_t)(unsigned)evb.x << 6));
            s0 += va * bf16_lo(xa.x); s1 += va * bf16_hi(xa.x);
            s2 += va * bf16_lo(xa.y); s3 += va * bf16_hi(xa.y);
            s4 += va * bf16_lo(xa.z); s5 += va * bf16_hi(xa.z);
            s6 += va * bf16_lo(xa.w); s7 += va * bf16_hi(xa.w);
            s0 += vb * bf16_lo(xb.x); s1 += vb * bf16_hi(xb.x);
            s2 += vb * bf16_lo(xb.y); s3 += vb * bf16_hi(xb.y);
            s4 += vb * bf16_lo(xb.z); s5 += vb * bf16_hi(xb.z);
            s6 += vb * bf16_lo(xb.w); s7 += vb * bf16_hi(xb.w);
        }
        // combine octet partials: after xor 8/16/32 every lane has the total
        s0 += __shfl_xor(s0, 8); s0 += __shfl_xor(s0, 16); s0 += __shfl_xor(s0, 32);
        s1 += __shfl_xor(s1, 8); s1 += __shfl_xor(s1, 16); s1 += __shfl_xor(s1, 32);
        s2 += __shfl_xor(s2, 8); s2 += __shfl_xor(s2, 16); s2 += __shfl_xor(s2, 32);
        s3 += __shfl_xor(s3, 8); s3 += __shfl_xor(s3, 16); s3 += __shfl_xor(s3, 32);
        s4 += __shfl_xor(s4, 8); s4 += __shfl_xor(s4, 16); s4 += __shfl_xor(s4, 32);
        s5 += __shfl_xor(s5, 8); s5 += __shfl_xor(s5, 16); s5 += __shfl_xor(s5, 32);
        s6 += __shfl_xor(s6, 8); s6 += __shfl_xor(s6, 16); s6 += __shfl_xor(s6, 32);
        s7 += __shfl_xor(s7, 8); s7 += __shfl_xor(s7, 16); s7 += __shfl_xor(s7, 32);
        if (lane < 8) {                          // o == 0, t == lane
            if (write_y) {
                uint4 cv;
                cv.x = (unsigned)f32_to_bf16_rne(s0) |
                       ((unsigned)f32_to_bf16_rne(s1) << 16);
                cv.y = (unsigned)f32_to_bf16_rne(s2) |
                       ((unsigned)f32_to_bf16_rne(s3) << 16);
                cv.z = (unsigned)f32_to_bf16_rne(s4) |
                       ((unsigned)f32_to_bf16_rne(s5) << 16);
                cv.w = (unsigned)f32_to_bf16_rne(s6) |
                       ((unsigned)f32_to_bf16_rne(s7) << 16);
                ((uint4*)(y + ((size_t)r << 6)))[t] = cv;
            }
            float4* a4 = (float4*)(acc + ((size_t)r << 6) + (t << 3));
            float4 a0 = a4[0];
            float4 a1 = a4[1];
            a0.x += 0.25f * s0; a0.y += 0.25f * s1;
            a0.z += 0.25f * s2; a0.w += 0.25f * s3;
            a1.x += 0.25f * s4; a1.y += 0.25f * s5;
            a1.z += 0.25f * s6; a1.w += 0.25f * s7;
            a4[0] = a0;
            a4[1] = a1;
        }
    }
}

// ---------------- fallback (scatter-atomic, f32 path) ----------------

__global__ void init_f32_kernel(const float* __restrict__ user_emb,
                                const float* __restrict__ item_emb,
                                float* __restrict__ cur,
                                float* __restrict__ acc) {
    const int total = N_CNT * DIM / 4;
    const int ubound = U_CNT * DIM / 4;
    const float4* ue = (const float4*)user_emb;
    const float4* ie = (const float4*)item_emb;
    float4* c4 = (float4*)cur;
    float4* a4 = (float4*)acc;
    for (int i = blockIdx.x * blockDim.x + threadIdx.x; i < total;
         i += gridDim.x * blockDim.x) {
        float4 v = (i < ubound) ? ue[i] : ie[i - ubound];
        c4[i] = v;
        float4 a = v;
        a.x *= 0.25f; a.y *= 0.25f; a.z *= 0.25f; a.w *= 0.25f;
        a4[i] = a;
    }
}

__global__ void spmm_atomic_kernel(const float* __restrict__ val,
                                   const int* __restrict__ row,
                                   const int* __restrict__ col,
                                   const float* __restrict__ x,
                                   float* __restrict__ y) {
    const int lane = threadIdx.x & 63;
    const int gw = (blockIdx.x * blockDim.x + threadIdx.x) >> 6;
    const int totalWaves = (gridDim.x * blockDim.x) >> 6;
    for (int base = gw * 64; base < NNZ_CNT; base += totalWaves * 64) {
        const int e = base + lane;
        const float v = val[e];
        const int r = row[e];
        const int c = col[e];
        #pragma unroll 8
        for (int k = 0; k < 64; ++k) {
            const float vk = __shfl(v, k);
            const int rk = __shfl(r, k);
            const int ck = __shfl(c, k);
            atomicAdd(&y[rk * DIM + lane], vk * x[ck * DIM + lane]);
        }
    }
}

__global__ void accum_scale_kernel(float* __restrict__ acc,
                                   const float* __restrict__ nxt,
                                   float wacc) {
    const int total = N_CNT * DIM / 4;
    float4* a4 = (float4*)acc;
    const float4* n4 = (const float4*)nxt;
    for (int i = blockIdx.x * blockDim.x + threadIdx.x; i < total;
         i += gridDim.x * blockDim.x) {
        float4 a = a4[i];
        const float4 n = n4[i];
        a.x += wacc * n.x; a.y += wacc * n.y; a.z += wacc * n.z; a.w += wacc * n.w;
        a4[i] = a;
    }
}

// ---------------- launch ----------------

extern "C" void kernel_launch(void* const* d_in, const int* in_sizes, int n_in,
                              void* d_out, int out_size, void* d_ws, size_t ws_size,
                              hipStream_t stream) {
    const float* user_emb  = (const float*)d_in[0];
    const float* item_emb  = (const float*)d_in[1];
    const float* adj_val   = (const float*)d_in[2];
    const int*   adj_row   = (const int*)d_in[3];
    const int*   adj_col   = (const int*)d_in[4];
    const int*   users     = (const int*)d_in[5];
    const int*   pos_items = (const int*)d_in[6];
    const int*   neg_items = (const int*)d_in[7];
    // d_in[8] = num_layers, fixed at 3 (device scalar; host read would break
    // graph capture).

    float* out       = (float*)d_out;
    float* out_sel   = out;
    float* final_emb = out + (size_t)3 * NSEL * DIM;   // u_g then i_g
    float* acc       = final_emb;

    const size_t NBH = (size_t)N_CNT * DIM * 2;        // bf16 buf: 19,200,000
    char* ws = (char*)d_ws;
    // etmp (padded, 54.5MB) occupies ws[0:offE]; bufA/bufB (bf16, 38.4MB)
    // alias its front and are only written after csr_sort consumed etmp.
    int2* etmp = (int2*)(ws + 0);
    unsigned short* bufA = (unsigned short*)(ws + 0);
    unsigned short* bufB = (unsigned short*)(ws + NBH);

    const size_t offE    = (size_t)NBKT * BCAP * 8;          // 54,525,952
    const size_t offG    = offE + (size_t)NNZ_CNT * 8;       // gcnt 2KB
    const size_t offBoff = offG + 4096;                      // boff 2052B
    const size_t offOff  = offBoff + 4096;                   // off[N+1]
    const size_t needed  = offOff + (size_t)(N_CNT + 1) * 4 + 64;

    if (ws_size >= needed) {
        int2* edges = (int2*)(ws + offE);
        int*  gcnt  = (int*)(ws + offG);
        int*  boff  = (int*)(ws + offBoff);
        int*  offp  = (int*)(ws + offOff);

        (void)hipMemsetAsync(gcnt, 0, NBKT * sizeof(int), stream);
        bin_scatter_kernel<<<BIN_BLK, BIN_THR, 0, stream>>>(adj_val, adj_row,
                                                            adj_col, gcnt,
                                                            etmp);
        scan_tot_kernel<<<1, NBKT, 0, stream>>>(gcnt, boff);
        csr_sort_kernel<<<NBKT, 1024, 0, stream>>>(etmp, gcnt, boff, edges,
                                                   offp);

        init_kernel<<<2048, 256, 0, stream>>>(user_emb, item_emb, bufA, acc);

        unsigned short* cur = bufA;
        unsigned short* nxt = bufB;
        for (int l = 0; l < 3; ++l) {
            spmm_csr_kernel<<<2048, 256, 0, stream>>>(edges, offp, cur, nxt, acc,
                                                      (l < 2) ? 1 : 0);
            unsigned short* t = cur; cur = nxt; nxt = t;
        }
    } else {
        // f32 scatter-atomic fallback (needs 2*38.4MB of ws)
        float* fA = (float*)(ws + 0);
        float* fB = (float*)(ws + (size_t)N_CNT * DIM * sizeof(float));
        init_f32_kernel<<<2048, 256, 0, stream>>>(user_emb, item_emb, fA, acc);
        float* cur = fA;
        float* nxt = fB;
        for (int l = 0; l < 3; ++l) {
            (void)hipMemsetAsync(nxt, 0, (size_t)N_CNT * DIM * sizeof(float),
                                 stream);
            spmm_atomic_kernel<<<2048, 256, 0, stream>>>(adj_val, adj_row,
                                                         adj_col, cur, nxt);
            accum_scale_kernel<<<2048, 256, 0, stream>>>(acc, nxt, 0.25f);
            float* t = cur; cur = nxt; nxt = t;
        }
    }

    gather_kernel<<<768, 256, 0, stream>>>(final_emb, users, pos_items,
                                           neg_items, out_sel);
}